// Round 8
// baseline (75.424 us; speedup 1.0000x reference)
//
#include <hip/hip_runtime.h>

// energy_bc_loss: B=4, C=3, H=W=256
// loss = (9 * sum(18*s2 - 2*s1^2) + 0.001 * sum((y - t_slide)^2)) / 64516
// (w_sum == 9 exactly: centered patches sum to zero -> quadratic form vanishes)
//
// memset + 5 kernels:
//   k_bc_band  (256 blk): 15x15 max of channel-max via row-band halo in LDS,
//                         + per-batch key histogram + smoothness partials
//   k_gather   ( 64 blk): redundant per-block hist scan -> T,prefix; classify
//                         own pixels -> sure idx + threshold-bucket candidates
//   k_resolve  (  4 blk): (value,index) bisect over LDS candidates -> 65 idx,
//                         + atmosphere scale partial sums
//   k_nbc_band (256 blk): norm channel-max 15x15 max band + data-term partials
//   k_final    (  1 blk): combine partials
// r7 crash: k_gather used seg*4096+q*1024 stride (4x OOB; meta overflow ->
// wild idxhead/cand writes). Fixed: seg*1024+q*256+tid (1024 uint4/segment).

#define NBAT 4
#define NCH 3
#define NH 256
#define NW 256
#define NHW (NH*NW)
#define NPIX 65            // int(0.001*256*256)
#define RAD 7              // 15x15 window
#define NOUT 254
#define NPOS (NOUT*NOUT)   // 64516
#define NDTOT (NBAT*NPOS)  // 258064
#define EPSF 1e-5f
#define KLO 0x3F000000u    // 0.5f (bc = max of 675 uniforms, always > 0.5)
#define NBUCK 4096
#define CAP 4096
#define BANDH 4
#define HROWS (BANDH + 2*RAD)   // 18 staged rows per band

#define BK(k) (((k) <= KLO) ? 0u : (((k) - KLO) >> 11))

// meta: [0..3]=sure count per batch, [4..7]=candidate count per batch

// ---------- K1: bc = 15x15 max of channel-max (band+halo), hist, nd partials ----------
__global__ __launch_bounds__(256) void k_bc_band(const float* __restrict__ img,
        const float* __restrict__ yp, float* __restrict__ bc,
        unsigned* __restrict__ hist, float* __restrict__ nd_part) {
    __shared__ float rows[HROWS][NW];
    __shared__ float hm[HROWS][NW];
    __shared__ unsigned lh[NBUCK];
    __shared__ float red[256];
    const int blk = blockIdx.x, tid = threadIdx.x;
    const int b = blk >> 6, r0 = (blk & 63) * BANDH;

    for (int j = tid; j < NBUCK; j += 256) lh[j] = 0u;

    const float* ib = img + (size_t)b * NCH * NHW;
    #pragma unroll
    for (int rr = 0; rr < HROWS; ++rr) {
        int ry = min(max(r0 - RAD + rr, 0), NH - 1);   // clamped dup rows: max-safe
        const float* p = ib + ry * NW + tid;
        rows[rr][tid] = fmaxf(fmaxf(p[0], p[NHW]), p[2 * NHW]);
    }

    // smoothness partials (independent of band work; depends only on yp)
    float ndp = 0.f;
    #pragma unroll
    for (int q = 0; q < 4; ++q) {
        int i = blk * 256 + tid + q * 65536;
        if (i < NDTOT) {
            int bb = i / NPOS, n = i % NPOS;
            int r = n / NOUT, cc = n % NOUT;
            const float* base2 = yp + bb * NHW + r * NW + cc;
            float s1 = 0.f, s2 = 0.f;
            #pragma unroll
            for (int dy = 0; dy < 3; ++dy)
                #pragma unroll
                for (int dx = 0; dx < 3; ++dx) {
                    float t = base2[dy * NW + dx];
                    s1 += t; s2 += t * t;
                }
            ndp += 18.f * s2 - 2.f * s1 * s1;
        }
    }
    __syncthreads();

    const int x0 = max(tid - RAD, 0), x1 = min(tid + RAD, NW - 1);
    #pragma unroll
    for (int rr = 0; rr < HROWS; ++rr) {
        float m = rows[rr][x0];
        for (int xx = x0 + 1; xx <= x1; ++xx) m = fmaxf(m, rows[rr][xx]);
        hm[rr][tid] = m;
    }
    __syncthreads();

    #pragma unroll
    for (int k = 0; k < BANDH; ++k) {
        float m = hm[k][tid];
        #pragma unroll
        for (int rr = 1; rr < 15; ++rr) m = fmaxf(m, hm[k + rr][tid]);
        bc[b * NHW + (r0 + k) * NW + tid] = m;
        atomicAdd(&lh[BK(__float_as_uint(m))], 1u);
    }
    __syncthreads();

    unsigned* gh = hist + b * NBUCK;
    for (int j = tid; j < NBUCK; j += 256) {
        unsigned c = lh[j];
        if (c) atomicAdd(&gh[j], c);
    }

    red[tid] = ndp; __syncthreads();
    for (int s = 128; s > 0; s >>= 1) {
        if (tid < s) red[tid] += red[tid + s];
        __syncthreads();
    }
    if (tid == 0) nd_part[blk] = red[0];
}

// ---------- K2: redundant hist scan + classify own pixels ----------
__global__ __launch_bounds__(256) void k_gather(const float* __restrict__ bc,
        const unsigned* __restrict__ hist, unsigned* __restrict__ meta,
        int* __restrict__ idxhead, unsigned* __restrict__ cand) {
    __shared__ unsigned sw[4];
    __shared__ unsigned sT;
    const int blk = blockIdx.x, tid = threadIdx.x, lane = tid & 63, wid = tid >> 6;
    const int b = blk >> 4, seg = blk & 15;

    // scan 4096 buckets (every block, deterministic): thread owns 16 buckets
    const unsigned* h = hist + b * NBUCK + tid * 16;
    unsigned hv0 = h[0], hv1 = h[1], hv2 = h[2], hv3 = h[3];
    unsigned hv4 = h[4], hv5 = h[5], hv6 = h[6], hv7 = h[7];
    unsigned hv8 = h[8], hv9 = h[9], hv10 = h[10], hv11 = h[11];
    unsigned hv12 = h[12], hv13 = h[13], hv14 = h[14], hv15 = h[15];
    unsigned s = hv0+hv1+hv2+hv3+hv4+hv5+hv6+hv7+hv8+hv9+hv10+hv11+hv12+hv13+hv14+hv15;
    unsigned is = s;
    for (int off = 1; off < 64; off <<= 1) {
        unsigned a = __shfl_up(is, off);
        if (lane >= off) is += a;
    }
    if (lane == 63) sw[wid] = is;
    __syncthreads();
    unsigned wpre = 0;
    for (int w = 0; w < wid; ++w) wpre += sw[w];
    unsigned c = wpre + is - s;           // exclusive prefix over buckets
    #define STEP(hk, kk) { unsigned nb = c + (hk); \
        if (c < NPIX && nb >= NPIX) sT = tid * 16 + (kk); c = nb; }
    STEP(hv0,0) STEP(hv1,1) STEP(hv2,2) STEP(hv3,3) STEP(hv4,4) STEP(hv5,5)
    STEP(hv6,6) STEP(hv7,7) STEP(hv8,8) STEP(hv9,9) STEP(hv10,10) STEP(hv11,11)
    STEP(hv12,12) STEP(hv13,13) STEP(hv14,14) STEP(hv15,15)
    #undef STEP
    __syncthreads();
    const unsigned T = sT;
    const unsigned klo2 = KLO + (T << 11);

    // classify this segment's 1024 uint4 (= 4096 pixels) of batch b
    const uint4* src4 = reinterpret_cast<const uint4*>(bc + b * NHW);
    #define CLASS1(key, ii) { unsigned bk = BK(key); \
        if (bk < T) { unsigned pp = atomicAdd(&meta[b], 1u); \
                      idxhead[b * NPIX + pp] = (int)(ii); } \
        else if (bk == T) { unsigned pp = atomicAdd(&meta[4 + b], 1u); \
            if (pp < CAP) { unsigned ko = ((key) > klo2) ? ((key) - klo2) : 0u; \
                            cand[b * CAP + pp] = (ko << 16) | (ii); } } }
    #pragma unroll
    for (int q = 0; q < 4; ++q) {
        int j = seg * 1024 + q * 256 + tid;       // r7 bug: was seg*4096+q*1024
        uint4 v = src4[j];
        unsigned gi = (unsigned)j * 4u;
        CLASS1(v.x, gi)
        CLASS1(v.y, gi + 1)
        CLASS1(v.z, gi + 2)
        CLASS1(v.w, gi + 3)
    }
    #undef CLASS1
}

// ---------- K3: bisect (value,index) codes; emit idx; scale partials ----------
__global__ __launch_bounds__(256) void k_resolve(const float* __restrict__ img,
        const unsigned* __restrict__ meta, const unsigned* __restrict__ cand,
        const int* __restrict__ idxhead, float* __restrict__ scl_sum) {
    __shared__ unsigned shm[CAP];
    __shared__ unsigned s_tot[32];
    __shared__ unsigned s_idx[NPIX];
    __shared__ unsigned s_emit;
    const int b = blockIdx.x, tid = threadIdx.x, lane = tid & 63, wid = tid >> 6;
    unsigned prefix = meta[b];                    // sure count, <= 64
    unsigned cnt = meta[4 + b]; if (cnt > CAP) cnt = CAP;
    unsigned need = NPIX - prefix;                // >= 1
    if (tid < (int)prefix) s_idx[tid] = (unsigned)idxhead[b * NPIX + tid];
    if (tid < 32) s_tot[tid] = 0u;
    if (tid == 0) s_emit = 0u;
    const unsigned* cb = cand + b * CAP;
    for (int j = tid; j < CAP; j += 256)
        shm[j] = ((unsigned)j < cnt) ? cb[j] : 0xFFFFFFFFu;
    __syncthreads();

    // u = min{v : count(code <= v) >= need}; codes unique (idx unique)
    unsigned lo = 0u, hi = (1u << 27) - 1u;
    int it = 0;
    while (lo < hi) {
        unsigned mid = lo + ((hi - lo) >> 1);
        unsigned cc = 0;
        #pragma unroll
        for (int k = 0; k < 16; ++k) cc += (shm[tid + k * 256] <= mid);
        for (int off = 32; off > 0; off >>= 1) cc += __shfl_down(cc, off);
        if (lane == 0) atomicAdd(&s_tot[it], cc);
        __syncthreads();
        if (s_tot[it] >= need) hi = mid; else lo = mid + 1;
        ++it;                                      // <= 27 iterations
    }
    unsigned u = lo;
    #pragma unroll
    for (int k = 0; k < 16; ++k) {
        unsigned v = shm[tid + k * 256];
        if (v <= u) {
            unsigned pos = prefix + atomicAdd(&s_emit, 1u);
            if (pos < NPIX) s_idx[pos] = v & 0xFFFFu;
        }
    }
    __syncthreads();

    // scale partials: plane p = bb*3+ch -> img + p*NHW; this block contributes
    // its batch's 65 indices to ALL 12 plane sums (reference reshape(-1) quirk)
    for (int p = wid; p < NBAT * NCH; p += 4) {
        const float* plane = img + (size_t)p * NHW;
        float v = plane[s_idx[lane]];
        if (lane == 0) v += plane[s_idx[64]];
        for (int off = 32; off > 0; off >>= 1) v += __shfl_down(v, off);
        if (lane == 0) atomicAdd(&scl_sum[p], v);
    }
}

// ---------- K4: t_slide band (norm channel-max 15x15) + data-term partials ----------
__global__ __launch_bounds__(256) void k_nbc_band(const float* __restrict__ img,
        const float* __restrict__ yp, const float* __restrict__ scl_sum,
        float* __restrict__ vd_part) {
    __shared__ float rows[HROWS][NW];
    __shared__ float hm[HROWS][NW];
    __shared__ float red[256];
    const int blk = blockIdx.x, tid = threadIdx.x;
    const int b = blk >> 6, r0 = (blk & 63) * BANDH;
    const float inv = 1.f / (float)(NBAT * NPIX);
    const float sc0 = 1.f / (1.f - scl_sum[b * 3 + 0] * inv + EPSF);
    const float sc1 = 1.f / (1.f - scl_sum[b * 3 + 1] * inv + EPSF);
    const float sc2 = 1.f / (1.f - scl_sum[b * 3 + 2] * inv + EPSF);

    const float* ib = img + (size_t)b * NCH * NHW;
    #pragma unroll
    for (int rr = 0; rr < HROWS; ++rr) {
        int ry = min(max(r0 - RAD + rr, 0), NH - 1);
        const float* p = ib + ry * NW + tid;
        float m = (1.f - p[0]) * sc0;
        m = fmaxf(m, (1.f - p[NHW]) * sc1);
        m = fmaxf(m, (1.f - p[2 * NHW]) * sc2);
        rows[rr][tid] = m;
    }
    __syncthreads();
    const int x0 = max(tid - RAD, 0), x1 = min(tid + RAD, NW - 1);
    #pragma unroll
    for (int rr = 0; rr < HROWS; ++rr) {
        float m = rows[rr][x0];
        for (int xx = x0 + 1; xx <= x1; ++xx) m = fmaxf(m, rows[rr][xx]);
        hm[rr][tid] = m;
    }
    __syncthreads();
    float vdp = 0.f;
    #pragma unroll
    for (int k = 0; k < BANDH; ++k) {
        float m = hm[k][tid];
        #pragma unroll
        for (int rr = 1; rr < 15; ++rr) m = fmaxf(m, hm[k + rr][tid]);
        float t = 1.f - m;
        float d = yp[b * NHW + (r0 + k) * NW + tid] - t;
        vdp += d * d;
    }
    red[tid] = vdp; __syncthreads();
    for (int s = 128; s > 0; s >>= 1) {
        if (tid < s) red[tid] += red[tid + s];
        __syncthreads();
    }
    if (tid == 0) vd_part[blk] = red[0];
}

// ---------- K5: final reduction of 256+256 partials ----------
__global__ __launch_bounds__(256) void k_final(const float* __restrict__ vd_part,
        const float* __restrict__ nd_part, float* __restrict__ out) {
    __shared__ double dv[256], dn[256];
    int t = threadIdx.x;
    dv[t] = (double)vd_part[t];
    dn[t] = (double)nd_part[t];
    __syncthreads();
    for (int s = 128; s > 0; s >>= 1) {
        if (t < s) { dv[t] += dv[t + s]; dn[t] += dn[t + s]; }
        __syncthreads();
    }
    if (t == 0) out[0] = (float)((9.0 * dn[0] + 0.001 * dv[0]) / (double)NPOS);
}

extern "C" void kernel_launch(void* const* d_in, const int* in_sizes, int n_in,
                              void* d_out, int out_size, void* d_ws, size_t ws_size,
                              hipStream_t stream) {
    const float* img = (const float*)d_in[0];   // (4,3,256,256)
    const float* yp  = (const float*)d_in[1];   // (4,1,256,256)
    float* out = (float*)d_out;

    char* ws = (char*)d_ws;
    float*    d_bc  = (float*)(ws);                              // 1 MiB
    unsigned* hist  = (unsigned*)(ws + (1 << 20));               // 64 KB
    unsigned* meta  = (unsigned*)(ws + (1 << 20) + 65536);       // 32 B (zeroed)
    float*    scl   = (float*)(ws + (1 << 20) + 65536 + 64);     // 48 B (zeroed)
    int*      idxh  = (int*)(ws + (1 << 20) + 65536 + 128);      // 1040 B
    unsigned* cand  = (unsigned*)(ws + (1 << 20) + 65536 + 2048);// 64 KB
    float*    ndp   = (float*)(ws + (1 << 20) + 65536 + 2048 + 65536);       // 1 KB
    float*    vdp   = (float*)(ws + (1 << 20) + 65536 + 2048 + 65536 + 1024);// 1 KB

    hipMemsetAsync(hist, 0, 65536 + 128, stream);   // hist + meta + scl

    k_bc_band<<<NBAT * 64, 256, 0, stream>>>(img, yp, d_bc, hist, ndp);
    k_gather<<<NBAT * 16, 256, 0, stream>>>(d_bc, hist, meta, idxh, cand);
    k_resolve<<<NBAT, 256, 0, stream>>>(img, meta, cand, idxh, scl);
    k_nbc_band<<<NBAT * 64, 256, 0, stream>>>(img, yp, scl, vdp);
    k_final<<<1, 256, 0, stream>>>(vdp, ndp, out);
}